// Round 8
// baseline (185.628 us; speedup 1.0000x reference)
//
#include <hip/hip_runtime.h>
#include <math.h>

#define NL 12
#define NB 2
#define NT 2048
#define ND 2048
#define NC 4
#define NH 48
#define NBT (NB*NT)                 // 4096 tokens
#define BTD ((long)NBT*(long)ND)    // 8388608
#define TOK 8                       // tokens per block in dw_kernel

typedef float fx4 __attribute__((ext_vector_type(4)));

__device__ __forceinline__ float gelu_exact(float x) {
    return 0.5f * x * (1.0f + erff(x * 0.70710678118654752f));
}

// Kernel 1: dw[b,t,j] = (gelu(rms(x_cur) @ w1) @ w2)[j] + static_weight[j]
__global__ __launch_bounds__(256, 2)
void dw_kernel(const float* __restrict__ xs,
               const float* __restrict__ w1,
               const float* __restrict__ w2,
               const float* __restrict__ sw,
               float* __restrict__ dw_out) {
    __shared__ float xls[TOK][ND];      // 64 KB: 8 token rows of x_current
    __shared__ float rinv_s[TOK];
    __shared__ float y_s[TOK][NH];
    const int tid  = threadIdx.x;
    const int wave = tid >> 6;
    const int lane = tid & 63;

    const float* xcur = xs + (long)(NL - 1) * BTD + (long)blockIdx.x * TOK * ND;
    const float4* src = (const float4*)xcur;
    float4* dst = (float4*)&xls[0][0];
    #pragma unroll
    for (int i = 0; i < (TOK * ND / 4) / 256; ++i)
        dst[tid + i * 256] = src[tid + i * 256];
    __syncthreads();

    #pragma unroll
    for (int tt = 0; tt < 2; ++tt) {
        const int tok = wave * 2 + tt;
        float ss = 0.f;
        for (int d = lane; d < ND; d += 64) { float v = xls[tok][d]; ss += v * v; }
        #pragma unroll
        for (int off = 32; off; off >>= 1) ss += __shfl_xor(ss, off);
        if (lane == 0) rinv_s[tok] = rsqrtf(ss * (1.0f / ND) + 1e-6f);
    }
    __syncthreads();

    float rv[TOK];
    #pragma unroll
    for (int t = 0; t < TOK; ++t) rv[t] = rinv_s[t];

    float acc[TOK][12];
    #pragma unroll
    for (int t = 0; t < TOK; ++t)
        #pragma unroll
        for (int j = 0; j < 12; ++j) acc[t][j] = 0.f;

    const int h0 = wave * 12;
    for (int d = lane; d < ND; d += 64) {
        const float* wrow = w1 + (long)d * NH + h0;
        const float4 wA = *(const float4*)(wrow);
        const float4 wB = *(const float4*)(wrow + 4);
        const float4 wC = *(const float4*)(wrow + 8);
        #pragma unroll
        for (int t = 0; t < TOK; ++t) {
            const float xv = xls[t][d] * rv[t];
            acc[t][0]  += xv * wA.x; acc[t][1]  += xv * wA.y;
            acc[t][2]  += xv * wA.z; acc[t][3]  += xv * wA.w;
            acc[t][4]  += xv * wB.x; acc[t][5]  += xv * wB.y;
            acc[t][6]  += xv * wB.z; acc[t][7]  += xv * wB.w;
            acc[t][8]  += xv * wC.x; acc[t][9]  += xv * wC.y;
            acc[t][10] += xv * wC.z; acc[t][11] += xv * wC.w;
        }
    }
    #pragma unroll
    for (int t = 0; t < TOK; ++t)
        #pragma unroll
        for (int j = 0; j < 12; ++j) {
            float v = acc[t][j];
            #pragma unroll
            for (int off = 32; off; off >>= 1) v += __shfl_xor(v, off);
            acc[t][j] = v;
        }
    if (lane == 0) {
        #pragma unroll
        for (int t = 0; t < TOK; ++t)
            #pragma unroll
            for (int j = 0; j < 12; ++j)
                y_s[t][h0 + j] = acc[t][j];
    }
    __syncthreads();

    for (int i = tid; i < TOK * NH; i += 256) {
        float* p = &y_s[0][0];
        p[i] = gelu_exact(p[i]);
    }
    __syncthreads();

    for (int i = tid; i < TOK * NH; i += 256) {
        const int tok = i / NH;
        const int j   = i - tok * NH;
        float z = sw[j];
        #pragma unroll
        for (int h = 0; h < NH; ++h) z += y_s[tok][h] * w2[h * NH + j];
        dw_out[((long)blockIdx.x * TOK + tok) * NH + j] = z;
    }
}

// Kernel 2 v6: two-pass L2 re-read. Pass 1 streams the 12 rows (sumsq only,
// x NOT kept except x_cur). Pass 2 reloads the same addresses (L2-hot, ~5us
// turnover window) and aggregates. Register state ~90 VGPR -> (512,4) cap
// 128, 2 blocks/CU, 16 waves, spill-free by construction.
__global__ __launch_bounds__(512, 4)
void agg_kernel(const float* __restrict__ xs,
                const float* __restrict__ dw,
                const float* __restrict__ pre_scales,
                const float* __restrict__ post_scales,
                float* __restrict__ out) {
    const int tid  = threadIdx.x;
    const int wave = tid >> 6;
    const int lane = tid & 63;
    const int coff = tid * 4;          // fixed column slice per thread
    const long token = blockIdx.x;

    __shared__ float red[8][NL];       // per-wave partials, layer sumsq
    __shared__ float red2[8][NC];      // per-wave partials, way sumsq
    __shared__ float dws[NC * NL];     // dw transposed [l*4+c]

    if (tid < NC * NL) {
        const int c = tid / NL, l = tid - c * NL;
        dws[l * NC + c] = dw[token * (NC * NL) + tid];
    }

    // ---- pass 1: stream rows, sumsq only ----
    float ss[NL];
    fx4 xcur;
    #pragma unroll
    for (int l = 0; l < NL; ++l) {
        const fx4 v = *(const fx4*)(xs + (long)l * BTD + token * ND + coff);
        ss[l] = v.x*v.x + v.y*v.y + v.z*v.z + v.w*v.w;
        if (l == NL - 1) xcur = v;
    }
    #pragma unroll
    for (int l = 0; l < NL; ++l) {
        float v = ss[l];
        #pragma unroll
        for (int off = 32; off; off >>= 1) v += __shfl_xor(v, off);
        if (lane == 0) red[wave][l] = v;
    }
    __syncthreads();   // B1: red + dws visible

    float rvv[NL];
    {
        float s[NL];
        #pragma unroll
        for (int l = 0; l < NL; ++l) s[l] = 0.f;
        #pragma unroll
        for (int w = 0; w < 8; ++w) {
            const fx4 r0 = *(const fx4*)&red[w][0];
            const fx4 r1 = *(const fx4*)&red[w][4];
            const fx4 r2 = *(const fx4*)&red[w][8];
            s[0] += r0.x; s[1]  += r0.y; s[2]  += r0.z; s[3]  += r0.w;
            s[4] += r1.x; s[5]  += r1.y; s[6]  += r1.z; s[7]  += r1.w;
            s[8] += r2.x; s[9]  += r2.y; s[10] += r2.z; s[11] += r2.w;
        }
        #pragma unroll
        for (int l = 0; l < NL; ++l) rvv[l] = rsqrtf(s[l] * (1.0f / ND) + 1e-6f);
    }

    // ---- pass 2: reload rows (L2 hits) + aggregate 4 ways ----
    fx4 acc0 = (fx4)(0.f), acc1 = (fx4)(0.f), acc2 = (fx4)(0.f), acc3 = (fx4)(0.f);
    #pragma unroll
    for (int l = 0; l < NL; ++l) {
        const fx4 v = *(const fx4*)(xs + (long)l * BTD + token * ND + coff);
        const fx4 p = *(const fx4*)(pre_scales + (long)l * ND + coff);
        const fx4 w4 = *(const fx4*)&dws[l * NC];      // LDS broadcast
        const fx4 xn = v * rvv[l] * p;
        acc0 += w4.x * xn;
        acc1 += w4.y * xn;
        acc2 += w4.z * xn;
        acc3 += w4.w * xn;
    }

    // per-way sumsq, wave reduce
    {
        float q0 = acc0.x*acc0.x + acc0.y*acc0.y + acc0.z*acc0.z + acc0.w*acc0.w;
        float q1 = acc1.x*acc1.x + acc1.y*acc1.y + acc1.z*acc1.z + acc1.w*acc1.w;
        float q2 = acc2.x*acc2.x + acc2.y*acc2.y + acc2.z*acc2.z + acc2.w*acc2.w;
        float q3 = acc3.x*acc3.x + acc3.y*acc3.y + acc3.z*acc3.z + acc3.w*acc3.w;
        #pragma unroll
        for (int off = 32; off; off >>= 1) {
            q0 += __shfl_xor(q0, off);
            q1 += __shfl_xor(q1, off);
            q2 += __shfl_xor(q2, off);
            q3 += __shfl_xor(q3, off);
        }
        if (lane == 0) {
            red2[wave][0] = q0; red2[wave][1] = q1;
            red2[wave][2] = q2; red2[wave][3] = q3;
        }
    }
    __syncthreads();   // B2: red2 visible

    float r2[NC];
    {
        float s2[NC];
        #pragma unroll
        for (int c = 0; c < NC; ++c) s2[c] = 0.f;
        #pragma unroll
        for (int w = 0; w < 8; ++w) {
            const fx4 r = *(const fx4*)&red2[w][0];
            s2[0] += r.x; s2[1] += r.y; s2[2] += r.z; s2[3] += r.w;
        }
        #pragma unroll
        for (int c = 0; c < NC; ++c) r2[c] = rsqrtf(s2[c] * (1.0f / ND) + 1e-6f);
    }

    // ---- epilogue: out = rms(agg)*post + x_cur ----
    {
        const fx4 q0 = *(const fx4*)(post_scales + 0L * ND + coff);
        const fx4 q1 = *(const fx4*)(post_scales + 1L * ND + coff);
        const fx4 q2 = *(const fx4*)(post_scales + 2L * ND + coff);
        const fx4 q3 = *(const fx4*)(post_scales + 3L * ND + coff);
        const fx4 o0 = acc0 * r2[0] * q0 + xcur;
        const fx4 o1 = acc1 * r2[1] * q1 + xcur;
        const fx4 o2 = acc2 * r2[2] * q2 + xcur;
        const fx4 o3 = acc3 * r2[3] * q3 + xcur;
        __builtin_nontemporal_store(o0, (fx4*)(out + 0L * BTD + token * ND + coff));
        __builtin_nontemporal_store(o1, (fx4*)(out + 1L * BTD + token * ND + coff));
        __builtin_nontemporal_store(o2, (fx4*)(out + 2L * BTD + token * ND + coff));
        __builtin_nontemporal_store(o3, (fx4*)(out + 3L * BTD + token * ND + coff));
    }
}

extern "C" void kernel_launch(void* const* d_in, const int* in_sizes, int n_in,
                              void* d_out, int out_size, void* d_ws, size_t ws_size,
                              hipStream_t stream) {
    const float* xs   = (const float*)d_in[0];
    const float* w1   = (const float*)d_in[1];
    const float* w2   = (const float*)d_in[2];
    const float* sw   = (const float*)d_in[3];
    const float* pre  = (const float*)d_in[4];
    const float* post = (const float*)d_in[5];
    float* out   = (float*)d_out;
    float* dw_ws = (float*)d_ws;   // 4096*48 floats = 786 KB

    dw_kernel<<<NBT / TOK, 256, 0, stream>>>(xs, w1, w2, sw, dw_ws);
    agg_kernel<<<NBT, 512, 0, stream>>>(xs, dw_ws, pre, post, out);
}

// Round 9
// 184.834 us; speedup vs baseline: 1.0043x; 1.0043x over previous
//
#include <hip/hip_runtime.h>
#include <math.h>

#define NL 12
#define NB 2
#define NT 2048
#define ND 2048
#define NC 4
#define NH 48
#define NBT (NB*NT)                 // 4096 tokens
#define BTD ((long)NBT*(long)ND)    // 8388608
#define TOK 8                       // tokens per block in dw_kernel

typedef float fx4 __attribute__((ext_vector_type(4)));

__device__ __forceinline__ float gelu_exact(float x) {
    return 0.5f * x * (1.0f + erff(x * 0.70710678118654752f));
}

// Kernel 1: dw[b,t,j] = (gelu(rms(x_cur) @ w1) @ w2)[j] + static_weight[j]
__global__ __launch_bounds__(256, 2)
void dw_kernel(const float* __restrict__ xs,
               const float* __restrict__ w1,
               const float* __restrict__ w2,
               const float* __restrict__ sw,
               float* __restrict__ dw_out) {
    __shared__ float xls[TOK][ND];      // 64 KB: 8 token rows of x_current
    __shared__ float rinv_s[TOK];
    __shared__ float y_s[TOK][NH];
    const int tid  = threadIdx.x;
    const int wave = tid >> 6;
    const int lane = tid & 63;

    const float* xcur = xs + (long)(NL - 1) * BTD + (long)blockIdx.x * TOK * ND;
    const float4* src = (const float4*)xcur;
    float4* dst = (float4*)&xls[0][0];
    #pragma unroll
    for (int i = 0; i < (TOK * ND / 4) / 256; ++i)
        dst[tid + i * 256] = src[tid + i * 256];
    __syncthreads();

    #pragma unroll
    for (int tt = 0; tt < 2; ++tt) {
        const int tok = wave * 2 + tt;
        float ss = 0.f;
        for (int d = lane; d < ND; d += 64) { float v = xls[tok][d]; ss += v * v; }
        #pragma unroll
        for (int off = 32; off; off >>= 1) ss += __shfl_xor(ss, off);
        if (lane == 0) rinv_s[tok] = rsqrtf(ss * (1.0f / ND) + 1e-6f);
    }
    __syncthreads();

    float rv[TOK];
    #pragma unroll
    for (int t = 0; t < TOK; ++t) rv[t] = rinv_s[t];

    float acc[TOK][12];
    #pragma unroll
    for (int t = 0; t < TOK; ++t)
        #pragma unroll
        for (int j = 0; j < 12; ++j) acc[t][j] = 0.f;

    const int h0 = wave * 12;
    for (int d = lane; d < ND; d += 64) {
        const float* wrow = w1 + (long)d * NH + h0;
        const float4 wA = *(const float4*)(wrow);
        const float4 wB = *(const float4*)(wrow + 4);
        const float4 wC = *(const float4*)(wrow + 8);
        #pragma unroll
        for (int t = 0; t < TOK; ++t) {
            const float xv = xls[t][d] * rv[t];
            acc[t][0]  += xv * wA.x; acc[t][1]  += xv * wA.y;
            acc[t][2]  += xv * wA.z; acc[t][3]  += xv * wA.w;
            acc[t][4]  += xv * wB.x; acc[t][5]  += xv * wB.y;
            acc[t][6]  += xv * wB.z; acc[t][7]  += xv * wB.w;
            acc[t][8]  += xv * wC.x; acc[t][9]  += xv * wC.y;
            acc[t][10] += xv * wC.z; acc[t][11] += xv * wC.w;
        }
    }
    #pragma unroll
    for (int t = 0; t < TOK; ++t)
        #pragma unroll
        for (int j = 0; j < 12; ++j) {
            float v = acc[t][j];
            #pragma unroll
            for (int off = 32; off; off >>= 1) v += __shfl_xor(v, off);
            acc[t][j] = v;
        }
    if (lane == 0) {
        #pragma unroll
        for (int t = 0; t < TOK; ++t)
            #pragma unroll
            for (int j = 0; j < 12; ++j)
                y_s[t][h0 + j] = acc[t][j];
    }
    __syncthreads();

    for (int i = tid; i < TOK * NH; i += 256) {
        float* p = &y_s[0][0];
        p[i] = gelu_exact(p[i]);
    }
    __syncthreads();

    for (int i = tid; i < TOK * NH; i += 256) {
        const int tok = i / NH;
        const int j   = i - tok * NH;
        float z = sw[j];
        #pragma unroll
        for (int h = 0; h < NH; ++h) z += y_s[tok][h] * w2[h * NH + j];
        dw_out[((long)blockIdx.x * TOK + tok) * NH + j] = z;
    }
}

// Kernel 2 v7: R8's two-pass L2 re-read frame, ONE change: plain stores
// instead of nontemporal (A/B test: nt-store suspected of costing ~25us).
__global__ __launch_bounds__(512, 4)
void agg_kernel(const float* __restrict__ xs,
                const float* __restrict__ dw,
                const float* __restrict__ pre_scales,
                const float* __restrict__ post_scales,
                float* __restrict__ out) {
    const int tid  = threadIdx.x;
    const int wave = tid >> 6;
    const int lane = tid & 63;
    const int coff = tid * 4;          // fixed column slice per thread
    const long token = blockIdx.x;

    __shared__ float red[8][NL];       // per-wave partials, layer sumsq
    __shared__ float red2[8][NC];      // per-wave partials, way sumsq
    __shared__ float dws[NC * NL];     // dw transposed [l*4+c]

    if (tid < NC * NL) {
        const int c = tid / NL, l = tid - c * NL;
        dws[l * NC + c] = dw[token * (NC * NL) + tid];
    }

    // ---- pass 1: stream rows, sumsq only ----
    float ss[NL];
    fx4 xcur;
    #pragma unroll
    for (int l = 0; l < NL; ++l) {
        const fx4 v = *(const fx4*)(xs + (long)l * BTD + token * ND + coff);
        ss[l] = v.x*v.x + v.y*v.y + v.z*v.z + v.w*v.w;
        if (l == NL - 1) xcur = v;
    }
    #pragma unroll
    for (int l = 0; l < NL; ++l) {
        float v = ss[l];
        #pragma unroll
        for (int off = 32; off; off >>= 1) v += __shfl_xor(v, off);
        if (lane == 0) red[wave][l] = v;
    }
    __syncthreads();   // B1: red + dws visible

    float rvv[NL];
    {
        float s[NL];
        #pragma unroll
        for (int l = 0; l < NL; ++l) s[l] = 0.f;
        #pragma unroll
        for (int w = 0; w < 8; ++w) {
            const fx4 r0 = *(const fx4*)&red[w][0];
            const fx4 r1 = *(const fx4*)&red[w][4];
            const fx4 r2 = *(const fx4*)&red[w][8];
            s[0] += r0.x; s[1]  += r0.y; s[2]  += r0.z; s[3]  += r0.w;
            s[4] += r1.x; s[5]  += r1.y; s[6]  += r1.z; s[7]  += r1.w;
            s[8] += r2.x; s[9]  += r2.y; s[10] += r2.z; s[11] += r2.w;
        }
        #pragma unroll
        for (int l = 0; l < NL; ++l) rvv[l] = rsqrtf(s[l] * (1.0f / ND) + 1e-6f);
    }

    // ---- pass 2: reload rows (L2 hits) + aggregate 4 ways ----
    fx4 acc0 = (fx4)(0.f), acc1 = (fx4)(0.f), acc2 = (fx4)(0.f), acc3 = (fx4)(0.f);
    #pragma unroll
    for (int l = 0; l < NL; ++l) {
        const fx4 v = *(const fx4*)(xs + (long)l * BTD + token * ND + coff);
        const fx4 p = *(const fx4*)(pre_scales + (long)l * ND + coff);
        const fx4 w4 = *(const fx4*)&dws[l * NC];      // LDS broadcast
        const fx4 xn = v * rvv[l] * p;
        acc0 += w4.x * xn;
        acc1 += w4.y * xn;
        acc2 += w4.z * xn;
        acc3 += w4.w * xn;
    }

    // per-way sumsq, wave reduce
    {
        float q0 = acc0.x*acc0.x + acc0.y*acc0.y + acc0.z*acc0.z + acc0.w*acc0.w;
        float q1 = acc1.x*acc1.x + acc1.y*acc1.y + acc1.z*acc1.z + acc1.w*acc1.w;
        float q2 = acc2.x*acc2.x + acc2.y*acc2.y + acc2.z*acc2.z + acc2.w*acc2.w;
        float q3 = acc3.x*acc3.x + acc3.y*acc3.y + acc3.z*acc3.z + acc3.w*acc3.w;
        #pragma unroll
        for (int off = 32; off; off >>= 1) {
            q0 += __shfl_xor(q0, off);
            q1 += __shfl_xor(q1, off);
            q2 += __shfl_xor(q2, off);
            q3 += __shfl_xor(q3, off);
        }
        if (lane == 0) {
            red2[wave][0] = q0; red2[wave][1] = q1;
            red2[wave][2] = q2; red2[wave][3] = q3;
        }
    }
    __syncthreads();   // B2: red2 visible

    float r2[NC];
    {
        float s2[NC];
        #pragma unroll
        for (int c = 0; c < NC; ++c) s2[c] = 0.f;
        #pragma unroll
        for (int w = 0; w < 8; ++w) {
            const fx4 r = *(const fx4*)&red2[w][0];
            s2[0] += r.x; s2[1] += r.y; s2[2] += r.z; s2[3] += r.w;
        }
        #pragma unroll
        for (int c = 0; c < NC; ++c) r2[c] = rsqrtf(s2[c] * (1.0f / ND) + 1e-6f);
    }

    // ---- epilogue: out = rms(agg)*post + x_cur (PLAIN stores) ----
    {
        const fx4 q0 = *(const fx4*)(post_scales + 0L * ND + coff);
        const fx4 q1 = *(const fx4*)(post_scales + 1L * ND + coff);
        const fx4 q2 = *(const fx4*)(post_scales + 2L * ND + coff);
        const fx4 q3 = *(const fx4*)(post_scales + 3L * ND + coff);
        *(fx4*)(out + 0L * BTD + token * ND + coff) = acc0 * r2[0] * q0 + xcur;
        *(fx4*)(out + 1L * BTD + token * ND + coff) = acc1 * r2[1] * q1 + xcur;
        *(fx4*)(out + 2L * BTD + token * ND + coff) = acc2 * r2[2] * q2 + xcur;
        *(fx4*)(out + 3L * BTD + token * ND + coff) = acc3 * r2[3] * q3 + xcur;
    }
}

extern "C" void kernel_launch(void* const* d_in, const int* in_sizes, int n_in,
                              void* d_out, int out_size, void* d_ws, size_t ws_size,
                              hipStream_t stream) {
    const float* xs   = (const float*)d_in[0];
    const float* w1   = (const float*)d_in[1];
    const float* w2   = (const float*)d_in[2];
    const float* sw   = (const float*)d_in[3];
    const float* pre  = (const float*)d_in[4];
    const float* post = (const float*)d_in[5];
    float* out   = (float*)d_out;
    float* dw_ws = (float*)d_ws;   // 4096*48 floats = 786 KB

    dw_kernel<<<NBT / TOK, 256, 0, stream>>>(xs, w1, w2, sw, dw_ws);
    agg_kernel<<<NBT, 512, 0, stream>>>(xs, dw_ws, pre, post, out);
}